// Round 1
// baseline (337.912 us; speedup 1.0000x reference)
//
#include <hip/hip_runtime.h>
#include <hip/hip_bf16.h>

typedef __bf16 bf16;
typedef __attribute__((ext_vector_type(8))) __bf16 bf16x8;
typedef __attribute__((ext_vector_type(4))) float f32x4;

#define MFMA16(a, b, c) __builtin_amdgcn_mfma_f32_16x16x32_bf16((a), (b), (c), 0, 0, 0)

// Problem constants: N=4, L=2048, E=512, H=8, D=64, FF=2048, tokens = 8192.

// ---------------- weight conversion (fp32 [K][N] -> bf16 [N][K]) ----------------
__global__ void cvt_qkv_t(const float* __restrict__ wq, const float* __restrict__ wk,
                          const float* __restrict__ wv, bf16* __restrict__ dst) {
    int idx = blockIdx.x * 256 + threadIdx.x;     // [0, 1536*512)
    int j = idx >> 9;                             // output dim 0..1535
    int k = idx & 511;                            // input dim
    const float* src = (j < 512) ? wq : (j < 1024) ? wk : wv;
    dst[idx] = (bf16)src[k * 512 + (j & 511)];
}

template<int R, int C>
__global__ void cvt_t(const float* __restrict__ src, bf16* __restrict__ dst) {
    int idx = blockIdx.x * 256 + threadIdx.x;     // [0, R*C)
    int c = idx / R;
    int r = idx % R;
    dst[idx] = (bf16)src[r * C + c];              // dst[c][r] = src[r][c]
}

// ---------------- layernorm: fp32 in, bf16 out (one wave per row of 512) ----------------
__global__ void ln_kernel(const float* __restrict__ x, const float* __restrict__ g,
                          const float* __restrict__ b, bf16* __restrict__ out) {
    int row = blockIdx.x * 4 + (threadIdx.x >> 6);
    int lane = threadIdx.x & 63;
    const float4* xr = (const float4*)(x + (size_t)row * 512);
    float4 v0 = xr[lane];
    float4 v1 = xr[lane + 64];
    float s  = v0.x + v0.y + v0.z + v0.w + v1.x + v1.y + v1.z + v1.w;
    float sq = v0.x*v0.x + v0.y*v0.y + v0.z*v0.z + v0.w*v0.w
             + v1.x*v1.x + v1.y*v1.y + v1.z*v1.z + v1.w*v1.w;
    #pragma unroll
    for (int d = 1; d < 64; d <<= 1) { s += __shfl_xor(s, d); sq += __shfl_xor(sq, d); }
    float mean = s * (1.f / 512.f);
    float var  = sq * (1.f / 512.f) - mean * mean;
    float rs   = rsqrtf(var + 1e-5f);
    const float4* gv = (const float4*)g;
    const float4* bv = (const float4*)b;
    float4 ga = gv[lane], gb = gv[lane + 64];
    float4 ba = bv[lane], bb = bv[lane + 64];
    bf16* orow = out + (size_t)row * 512;
    int c0 = lane * 4;
    orow[c0 + 0]   = (bf16)((v0.x - mean) * rs * ga.x + ba.x);
    orow[c0 + 1]   = (bf16)((v0.y - mean) * rs * ga.y + ba.y);
    orow[c0 + 2]   = (bf16)((v0.z - mean) * rs * ga.z + ba.z);
    orow[c0 + 3]   = (bf16)((v0.w - mean) * rs * ga.w + ba.w);
    orow[c0 + 256] = (bf16)((v1.x - mean) * rs * gb.x + bb.x);
    orow[c0 + 257] = (bf16)((v1.y - mean) * rs * gb.y + bb.y);
    orow[c0 + 258] = (bf16)((v1.z - mean) * rs * gb.z + bb.z);
    orow[c0 + 259] = (bf16)((v1.w - mean) * rs * gb.w + bb.w);
}

// ---------------- GEMM: C[M][ND] = A[M][KD] @ Bt[ND][KD]^T, 128x128 tile ----------------
// EPI: 0 = store bf16; 1 = +bias +resid -> fp32; 2 = +bias, SiLU -> bf16
template<int KD, int ND, int EPI>
__global__ __launch_bounds__(256, 2) void gemm_k(
        const bf16* __restrict__ A, const bf16* __restrict__ Bt,
        const float* __restrict__ bias, const float* __restrict__ resid,
        void* __restrict__ outp) {
    __shared__ bf16 As[128][72];   // +8 pad: rows stay 16B aligned, <=2-way banks
    __shared__ bf16 Bs[128][72];
    const int bm = blockIdx.x, bn = blockIdx.y;
    const int tid = threadIdx.x;
    const int wave = tid >> 6, lane = tid & 63;
    const int wm = (wave >> 1) * 64, wn = (wave & 1) * 64;
    const int lr = lane & 15, lq = lane >> 4;
    f32x4 acc[4][4] = {};
    const bf16* Ab = A + (size_t)bm * 128 * KD;
    const bf16* Bb = Bt + (size_t)bn * 128 * KD;
    for (int k0 = 0; k0 < KD; k0 += 64) {
        __syncthreads();
        #pragma unroll
        for (int i = 0; i < 4; i++) {
            int c = tid + i * 256;
            int r = c >> 3, cc = (c & 7) * 8;
            *(uint4*)&As[r][cc] = *(const uint4*)&Ab[(size_t)r * KD + k0 + cc];
            *(uint4*)&Bs[r][cc] = *(const uint4*)&Bb[(size_t)r * KD + k0 + cc];
        }
        __syncthreads();
        #pragma unroll
        for (int ks = 0; ks < 2; ks++) {
            bf16x8 af[4], bfr[4];
            #pragma unroll
            for (int mi = 0; mi < 4; mi++)
                af[mi] = *(const bf16x8*)&As[wm + mi * 16 + lr][ks * 32 + lq * 8];
            #pragma unroll
            for (int ni = 0; ni < 4; ni++)
                bfr[ni] = *(const bf16x8*)&Bs[wn + ni * 16 + lr][ks * 32 + lq * 8];
            #pragma unroll
            for (int mi = 0; mi < 4; mi++)
                #pragma unroll
                for (int ni = 0; ni < 4; ni++)
                    acc[mi][ni] = MFMA16(af[mi], bfr[ni], acc[mi][ni]);
        }
    }
    #pragma unroll
    for (int mi = 0; mi < 4; mi++)
        #pragma unroll
        for (int ni = 0; ni < 4; ni++)
            #pragma unroll
            for (int r = 0; r < 4; r++) {
                int row = bm * 128 + wm + mi * 16 + lq * 4 + r;
                int col = bn * 128 + wn + ni * 16 + lr;
                float v = acc[mi][ni][r];
                size_t off = (size_t)row * ND + col;
                if constexpr (EPI == 0) {
                    ((bf16*)outp)[off] = (bf16)v;
                } else if constexpr (EPI == 1) {
                    ((float*)outp)[off] = v + bias[col] + resid[off];
                } else {
                    v += bias[col];
                    v = v / (1.f + __expf(-v));   // SiLU
                    ((bf16*)outp)[off] = (bf16)v;
                }
            }
}

// ---------------- flash attention: qkv packed [8192][1536], out bf16 [8192][512] ----------------
__global__ __launch_bounds__(256, 2) void attn_kernel(const bf16* __restrict__ qkv,
                                                      bf16* __restrict__ aout) {
    __shared__ bf16 Ks[128][72];       // K tile [key][d]
    __shared__ bf16 Vs[64][136];       // V tile transposed [d][key]
    __shared__ bf16 Ps[4][32][136];    // per-wave P in A-operand layout [m][key]
    const int b = blockIdx.x;          // 512 = (n*8+h)*16 + qt
    const int qt = b & 15;
    const int nh = b >> 4;
    const int n = nh >> 3, h = nh & 7;
    const int tid = threadIdx.x, w = tid >> 6, lane = tid & 63;
    const int lr = lane & 15, lq = lane >> 4;
    const float scale = 0.04419417382415922f;   // 512^-0.5 (NOT head_dim)

    // Q fragments straight from global (each lane's 16B is contiguous)
    const bf16* Qbase = qkv + (size_t)(n * 2048 + qt * 128) * 1536 + h * 64;
    bf16x8 qf[2][2];
    #pragma unroll
    for (int mi = 0; mi < 2; mi++)
        #pragma unroll
        for (int kk = 0; kk < 2; kk++)
            qf[mi][kk] = *(const bf16x8*)&Qbase[(size_t)(w * 32 + mi * 16 + lr) * 1536 + kk * 32 + lq * 8];

    f32x4 o_acc[2][4] = {};
    float m_i[2][4], l_i[2][4];
    #pragma unroll
    for (int mi = 0; mi < 2; mi++)
        #pragma unroll
        for (int r = 0; r < 4; r++) { m_i[mi][r] = -1e30f; l_i[mi][r] = 0.f; }

    for (int kt = 0; kt < 16; kt++) {
        const bf16* Kbase = qkv + (size_t)(n * 2048 + kt * 128) * 1536 + 512 + h * 64;
        const bf16* Vbase = Kbase + 512;
        __syncthreads();   // protect Ks/Vs against previous iteration's readers
        #pragma unroll
        for (int i = 0; i < 4; i++) {
            int c = tid + i * 256;
            int r = c >> 3, cc = (c & 7) * 8;
            *(uint4*)&Ks[r][cc] = *(const uint4*)&Kbase[(size_t)r * 1536 + cc];
        }
        #pragma unroll
        for (int i = 0; i < 4; i++) {
            int c = tid + i * 256;
            int key = c >> 3, dq = (c & 7) * 8;
            bf16x8 vv = *(const bf16x8*)&Vbase[(size_t)key * 1536 + dq];
            #pragma unroll
            for (int j = 0; j < 8; j++) Vs[dq + j][key] = vv[j];
        }
        __syncthreads();

        // S = Q @ K^T : per wave 32 rows x 128 keys
        f32x4 s[2][8] = {};
        #pragma unroll
        for (int kk = 0; kk < 2; kk++)
            #pragma unroll
            for (int nj = 0; nj < 8; nj++) {
                bf16x8 kf = *(const bf16x8*)&Ks[nj * 16 + lr][kk * 32 + lq * 8];
                s[0][nj] = MFMA16(qf[0][kk], kf, s[0][nj]);
                s[1][nj] = MFMA16(qf[1][kk], kf, s[1][nj]);
            }

        // online softmax (fp32); C-layout row = lq*4+r, col = lr
        #pragma unroll
        for (int mi = 0; mi < 2; mi++)
            #pragma unroll
            for (int r = 0; r < 4; r++) {
                float mx = -1e30f;
                #pragma unroll
                for (int nj = 0; nj < 8; nj++) {
                    s[mi][nj][r] *= scale;
                    mx = fmaxf(mx, s[mi][nj][r]);
                }
                #pragma unroll
                for (int d = 1; d < 16; d <<= 1) mx = fmaxf(mx, __shfl_xor(mx, d));
                float mnew = fmaxf(m_i[mi][r], mx);
                float alpha = __expf(m_i[mi][r] - mnew);
                m_i[mi][r] = mnew;
                float rsum = 0.f;
                #pragma unroll
                for (int nj = 0; nj < 8; nj++) {
                    float p = __expf(s[mi][nj][r] - mnew);
                    s[mi][nj][r] = p;
                    rsum += p;
                }
                #pragma unroll
                for (int d = 1; d < 16; d <<= 1) rsum += __shfl_xor(rsum, d);
                l_i[mi][r] = l_i[mi][r] * alpha + rsum;
                #pragma unroll
                for (int nj = 0; nj < 4; nj++) o_acc[mi][nj][r] *= alpha;
                // C-layout -> A-layout transpose via per-wave LDS
                #pragma unroll
                for (int nj = 0; nj < 8; nj++)
                    Ps[w][mi * 16 + lq * 4 + r][nj * 16 + lr] = (bf16)s[mi][nj][r];
            }

        // O += P @ V (k-dim = 128 keys)
        #pragma unroll
        for (int kk = 0; kk < 4; kk++) {
            bf16x8 pf0 = *(const bf16x8*)&Ps[w][lr][kk * 32 + lq * 8];
            bf16x8 pf1 = *(const bf16x8*)&Ps[w][16 + lr][kk * 32 + lq * 8];
            #pragma unroll
            for (int nj = 0; nj < 4; nj++) {
                bf16x8 vf = *(const bf16x8*)&Vs[nj * 16 + lr][kk * 32 + lq * 8];
                o_acc[0][nj] = MFMA16(pf0, vf, o_acc[0][nj]);
                o_acc[1][nj] = MFMA16(pf1, vf, o_acc[1][nj]);
            }
        }
    }

    #pragma unroll
    for (int mi = 0; mi < 2; mi++)
        #pragma unroll
        for (int r = 0; r < 4; r++) {
            float inv = 1.f / l_i[mi][r];
            int grow = n * 2048 + qt * 128 + w * 32 + mi * 16 + lq * 4 + r;
            #pragma unroll
            for (int nj = 0; nj < 4; nj++)
                aout[(size_t)grow * 512 + h * 64 + nj * 16 + lr] =
                    (bf16)(o_acc[mi][nj][r] * inv);
        }
}

extern "C" void kernel_launch(void* const* d_in, const int* in_sizes, int n_in,
                              void* d_out, int out_size, void* d_ws, size_t ws_size,
                              hipStream_t stream) {
    (void)in_sizes; (void)n_in; (void)out_size; (void)ws_size;
    const float* x   = (const float*)d_in[0];
    const float* wq  = (const float*)d_in[1];
    const float* wk  = (const float*)d_in[2];
    const float* wv  = (const float*)d_in[3];
    const float* wo  = (const float*)d_in[4];
    const float* bo  = (const float*)d_in[5];
    const float* g1  = (const float*)d_in[6];
    const float* b1  = (const float*)d_in[7];
    const float* g2  = (const float*)d_in[8];
    const float* b2  = (const float*)d_in[9];
    const float* w1  = (const float*)d_in[10];
    const float* bf1 = (const float*)d_in[11];
    const float* w2  = (const float*)d_in[12];
    const float* bf2 = (const float*)d_in[13];
    float* out = (float*)d_out;

    char* p = (char*)d_ws;
    bf16*  h1     = (bf16*)p;  p += (size_t)8192 * 512 * 2;    // LN1 out (reused for LN2 out)
    bf16*  qkvb   = (bf16*)p;  p += (size_t)8192 * 1536 * 2;   // packed Q|K|V
    bf16*  aout   = (bf16*)p;  p += (size_t)8192 * 512 * 2;    // attention out
    float* x2     = (float*)p; p += (size_t)8192 * 512 * 4;    // post-attn residual (fp32)
    bf16*  ff1    = (bf16*)p;  p += (size_t)8192 * 2048 * 2;   // SiLU(h@w1+b)
    bf16*  wqkv_t = (bf16*)p;  p += (size_t)1536 * 512 * 2;
    bf16*  wo_t   = (bf16*)p;  p += (size_t)512 * 512 * 2;
    bf16*  w1_t   = (bf16*)p;  p += (size_t)2048 * 512 * 2;
    bf16*  w2_t   = (bf16*)p;  p += (size_t)512 * 2048 * 2;

    cvt_qkv_t<<<3072, 256, 0, stream>>>(wq, wk, wv, wqkv_t);
    cvt_t<512, 512><<<1024, 256, 0, stream>>>(wo, wo_t);       // [512][512] -> [512][512]^T
    cvt_t<512, 2048><<<4096, 256, 0, stream>>>(w1, w1_t);      // [512][2048] -> [2048][512]
    cvt_t<2048, 512><<<4096, 256, 0, stream>>>(w2, w2_t);      // [2048][512] -> [512][2048]

    ln_kernel<<<2048, 256, 0, stream>>>(x, g1, b1, h1);
    gemm_k<512, 1536, 0><<<dim3(64, 12), 256, 0, stream>>>(h1, wqkv_t, nullptr, nullptr, qkvb);
    attn_kernel<<<512, 256, 0, stream>>>(qkvb, aout);
    gemm_k<512, 512, 1><<<dim3(64, 4), 256, 0, stream>>>(aout, wo_t, bo, x, x2);
    ln_kernel<<<2048, 256, 0, stream>>>(x2, g2, b2, h1);
    gemm_k<512, 2048, 2><<<dim3(64, 16), 256, 0, stream>>>(h1, w1_t, bf1, nullptr, ff1);
    gemm_k<2048, 512, 1><<<dim3(64, 4), 256, 0, stream>>>(ff1, w2_t, bf2, x2, out);
}

// Round 2
// 309.114 us; speedup vs baseline: 1.0932x; 1.0932x over previous
//
#include <hip/hip_runtime.h>
#include <hip/hip_bf16.h>

typedef __bf16 bf16;
typedef __attribute__((ext_vector_type(8))) __bf16 bf16x8;
typedef __attribute__((ext_vector_type(4))) float f32x4;

#define MFMA16(a, b, c) __builtin_amdgcn_mfma_f32_16x16x32_bf16((a), (b), (c), 0, 0, 0)

// Problem constants: N=4, L=2048, E=512, H=8, D=64, FF=2048, tokens = 8192.

// async global->LDS, 16B per lane; LDS dest = uniform base + lane*16 (HW rule)
__device__ __forceinline__ void load_lds16(const bf16* g, bf16* l) {
    __builtin_amdgcn_global_load_lds(
        (const __attribute__((address_space(1))) void*)g,
        (__attribute__((address_space(3))) void*)l, 16, 0, 0);
}

// ---------------- weight transpose via LDS tile (coalesced both sides) ----------------
// src fp32 [SR][SC] -> dst bf16 [SC][SR]; grid (SC/64, SR/64), block 256
template<int SR, int SC>
__global__ void cvt_t(const float* __restrict__ src, bf16* __restrict__ dst) {
    __shared__ float t[64][65];
    const int c0 = blockIdx.x * 64, r0 = blockIdx.y * 64;
    #pragma unroll
    for (int p = 0; p < 16; p++) {
        int lin = threadIdx.x + p * 256;
        int rr = lin >> 6, cc = lin & 63;
        t[rr][cc] = src[(size_t)(r0 + rr) * SC + c0 + cc];
    }
    __syncthreads();
    #pragma unroll
    for (int p = 0; p < 16; p++) {
        int lin = threadIdx.x + p * 256;
        int cc = lin >> 6, rr = lin & 63;            // consecutive tid -> consecutive rr
        dst[(size_t)(c0 + cc) * SR + r0 + rr] = (bf16)t[rr][cc];
    }
}

// packed QKV transpose: dst [1536][512], dst row j<512 from wq, <1024 wk, else wv
__global__ void cvt_qkv_t(const float* __restrict__ wq, const float* __restrict__ wk,
                          const float* __restrict__ wv, bf16* __restrict__ dst) {
    __shared__ float t[64][65];
    const int j0 = blockIdx.x * 64;                  // dst row tile (src col)
    const int k0 = blockIdx.y * 64;                  // src row tile
    const float* src = (j0 < 512) ? wq : (j0 < 1024) ? wk : wv;
    const int jc = j0 & 511;
    #pragma unroll
    for (int p = 0; p < 16; p++) {
        int lin = threadIdx.x + p * 256;
        int rr = lin >> 6, cc = lin & 63;
        t[rr][cc] = src[(size_t)(k0 + rr) * 512 + jc + cc];
    }
    __syncthreads();
    #pragma unroll
    for (int p = 0; p < 16; p++) {
        int lin = threadIdx.x + p * 256;
        int cc = lin >> 6, rr = lin & 63;
        dst[(size_t)(j0 + cc) * 512 + k0 + rr] = (bf16)t[rr][cc];
    }
}

// ---------------- layernorm: fp32 in, bf16 out (one wave per row of 512) ----------------
__global__ void ln_kernel(const float* __restrict__ x, const float* __restrict__ g,
                          const float* __restrict__ b, bf16* __restrict__ out) {
    int row = blockIdx.x * 4 + (threadIdx.x >> 6);
    int lane = threadIdx.x & 63;
    const float4* xr = (const float4*)(x + (size_t)row * 512);
    float4 v0 = xr[lane];
    float4 v1 = xr[lane + 64];
    float s  = v0.x + v0.y + v0.z + v0.w + v1.x + v1.y + v1.z + v1.w;
    float sq = v0.x*v0.x + v0.y*v0.y + v0.z*v0.z + v0.w*v0.w
             + v1.x*v1.x + v1.y*v1.y + v1.z*v1.z + v1.w*v1.w;
    #pragma unroll
    for (int d = 1; d < 64; d <<= 1) { s += __shfl_xor(s, d); sq += __shfl_xor(sq, d); }
    float mean = s * (1.f / 512.f);
    float var  = sq * (1.f / 512.f) - mean * mean;
    float rs   = rsqrtf(var + 1e-5f);
    const float4* gv = (const float4*)g;
    const float4* bv = (const float4*)b;
    float4 ga = gv[lane], gb = gv[lane + 64];
    float4 ba = bv[lane], bb = bv[lane + 64];
    bf16* orow = out + (size_t)row * 512;
    int c0 = lane * 4;
    orow[c0 + 0]   = (bf16)((v0.x - mean) * rs * ga.x + ba.x);
    orow[c0 + 1]   = (bf16)((v0.y - mean) * rs * ga.y + ba.y);
    orow[c0 + 2]   = (bf16)((v0.z - mean) * rs * ga.z + ba.z);
    orow[c0 + 3]   = (bf16)((v0.w - mean) * rs * ga.w + ba.w);
    orow[c0 + 256] = (bf16)((v1.x - mean) * rs * gb.x + bb.x);
    orow[c0 + 257] = (bf16)((v1.y - mean) * rs * gb.y + bb.y);
    orow[c0 + 258] = (bf16)((v1.z - mean) * rs * gb.z + bb.z);
    orow[c0 + 259] = (bf16)((v1.w - mean) * rs * gb.w + bb.w);
}

// ---------------- GEMM: C[M][ND] = A[M][KD] @ Bt[ND][KD]^T, 128x128 tile ----------------
// m97 recipe: global_load_lds width16, unpadded LDS, XOR swizzle slot^= (row&7)
// EPI: 0 = store bf16; 1 = +bias +resid -> fp32; 2 = +bias, SiLU -> bf16
template<int KD, int ND, int EPI>
__global__ __launch_bounds__(256, 3) void gemm_k(
        const bf16* __restrict__ A, const bf16* __restrict__ Bt,
        const float* __restrict__ bias, const float* __restrict__ resid,
        void* __restrict__ outp) {
    __shared__ bf16 As[128 * 64];
    __shared__ bf16 Bs[128 * 64];
    const int bm = blockIdx.x, bn = blockIdx.y;
    const int tid = threadIdx.x;
    const int w = tid >> 6, lane = tid & 63;
    const int wm = (w >> 1) * 64, wn = (w & 1) * 64;
    const int lr = lane & 15, lq = lane >> 4, lr7 = lane & 7;
    const int srow = lane >> 3, gslot = lane & 7;
    f32x4 acc[4][4] = {};
    const bf16* Ab = A + (size_t)bm * 128 * KD;
    const bf16* Bb = Bt + (size_t)bn * 128 * KD;
    const int gcol = (gslot ^ srow) * 8;             // swizzled global col chunk
    for (int k0 = 0; k0 < KD; k0 += 64) {
        __syncthreads();
        #pragma unroll
        for (int s = 0; s < 4; s++) {
            int rbase = w * 32 + s * 8;
            int row = rbase + srow;
            load_lds16(&Ab[(size_t)row * KD + k0 + gcol], &As[rbase * 64]);
            load_lds16(&Bb[(size_t)row * KD + k0 + gcol], &Bs[rbase * 64]);
        }
        __syncthreads();
        #pragma unroll
        for (int ks = 0; ks < 2; ks++) {
            bf16x8 af[4], bfr[4];
            #pragma unroll
            for (int mi = 0; mi < 4; mi++) {
                int row = wm + mi * 16 + lr;
                af[mi] = *(const bf16x8*)&As[row * 64 + (((ks * 4 + lq) ^ lr7) << 3)];
            }
            #pragma unroll
            for (int ni = 0; ni < 4; ni++) {
                int row = wn + ni * 16 + lr;
                bfr[ni] = *(const bf16x8*)&Bs[row * 64 + (((ks * 4 + lq) ^ lr7) << 3)];
            }
            #pragma unroll
            for (int mi = 0; mi < 4; mi++)
                #pragma unroll
                for (int ni = 0; ni < 4; ni++)
                    acc[mi][ni] = MFMA16(af[mi], bfr[ni], acc[mi][ni]);
        }
    }
    #pragma unroll
    for (int mi = 0; mi < 4; mi++)
        #pragma unroll
        for (int ni = 0; ni < 4; ni++)
            #pragma unroll
            for (int r = 0; r < 4; r++) {
                int row = bm * 128 + wm + mi * 16 + lq * 4 + r;
                int col = bn * 128 + wn + ni * 16 + lr;
                float v = acc[mi][ni][r];
                size_t off = (size_t)row * ND + col;
                if constexpr (EPI == 0) {
                    ((bf16*)outp)[off] = (bf16)v;
                } else if constexpr (EPI == 1) {
                    ((float*)outp)[off] = v + bias[col] + resid[off];
                } else {
                    v += bias[col];
                    v = v / (1.f + __expf(-v));   // SiLU
                    ((bf16*)outp)[off] = (bf16)v;
                }
            }
}

// ---------------- flash attention: qkv packed [8192][1536], out bf16 [8192][512] --------
// 512 threads = 8 waves x 16 Q-rows; K via global_load_lds (swizzled); V^T via
// conflict-free XOR-swizzled scatter; P round-trip through per-wave LDS.
__device__ __forceinline__ int vs_off(int d, int key) {
    int g = key >> 3;
    int sg = (g & 10) | ((g & 1) << 2) | ((g >> 2) & 1);  // swap bits 0<->2
    sg ^= (d >> 3) & 7;
    return d * 128 + sg * 8 + (key & 7);
}

__global__ __launch_bounds__(512, 4) void attn_kernel(const bf16* __restrict__ qkv,
                                                      bf16* __restrict__ aout) {
    __shared__ bf16 Ks[128 * 64];      // swizzled K tile [key][d]
    __shared__ bf16 Vs[64 * 128];      // swizzled V^T tile [d][key]
    __shared__ bf16 Ps[8][16][136];    // per-wave P in A-operand layout [m][key]
    const int b = blockIdx.x;          // 512 = (n*8+h)*16 + qt
    const int qt = b & 15;
    const int nh = b >> 4;
    const int n = nh >> 3, h = nh & 7;
    const int tid = threadIdx.x, w = tid >> 6, lane = tid & 63;
    const int lr = lane & 15, lq = lane >> 4, lr7 = lane & 7;
    const int srow = lane >> 3, gslot = lane & 7;
    const int gcol = (gslot ^ srow) * 8;
    const float scale = 0.04419417382415922f;   // 512^-0.5 (NOT head_dim)

    // Q fragments straight from global (each lane's 16B is contiguous)
    const bf16* Qbase = qkv + (size_t)(n * 2048 + qt * 128 + w * 16) * 1536 + h * 64;
    bf16x8 qf[2];
    qf[0] = *(const bf16x8*)&Qbase[(size_t)lr * 1536 + lq * 8];
    qf[1] = *(const bf16x8*)&Qbase[(size_t)lr * 1536 + 32 + lq * 8];

    f32x4 o_acc[4] = {};
    float m_i[4], l_i[4];
    #pragma unroll
    for (int r = 0; r < 4; r++) { m_i[r] = -1e30f; l_i[r] = 0.f; }

    for (int kt = 0; kt < 16; kt++) {
        const bf16* Kb = qkv + (size_t)(n * 2048 + kt * 128) * 1536 + 512 + h * 64;
        const bf16* Vb = Kb + 512;
        __syncthreads();   // protect Ks/Vs against previous iteration's readers
        #pragma unroll
        for (int s = 0; s < 2; s++) {               // K: 16 wave-loads, 2 per wave
            int rbase = w * 16 + s * 8;
            int row = rbase + srow;
            load_lds16(&Kb[(size_t)row * 1536 + gcol], &Ks[rbase * 64]);
        }
        #pragma unroll
        for (int i = 0; i < 2; i++) {               // V: vec load + swizzled scatter
            int c = tid + i * 512;
            int key = c >> 3, dq = (c & 7) * 8;
            bf16x8 vv = *(const bf16x8*)&Vb[(size_t)key * 1536 + dq];
            #pragma unroll
            for (int j = 0; j < 8; j++) Vs[vs_off(dq + j, key)] = vv[j];
        }
        __syncthreads();

        // S = Q @ K^T : per wave 16 rows x 128 keys
        f32x4 s[8] = {};
        #pragma unroll
        for (int kk = 0; kk < 2; kk++)
            #pragma unroll
            for (int nj = 0; nj < 8; nj++) {
                int row = nj * 16 + lr;
                bf16x8 kf = *(const bf16x8*)&Ks[row * 64 + (((kk * 4 + lq) ^ lr7) << 3)];
                s[nj] = MFMA16(qf[kk], kf, s[nj]);
            }

        // online softmax (fp32); C-layout row = lq*4+r, col = lr
        #pragma unroll
        for (int r = 0; r < 4; r++) {
            float mx = -1e30f;
            #pragma unroll
            for (int nj = 0; nj < 8; nj++) {
                s[nj][r] *= scale;
                mx = fmaxf(mx, s[nj][r]);
            }
            #pragma unroll
            for (int d = 1; d < 16; d <<= 1) mx = fmaxf(mx, __shfl_xor(mx, d));
            float mnew = fmaxf(m_i[r], mx);
            float alpha = __expf(m_i[r] - mnew);
            m_i[r] = mnew;
            float rsum = 0.f;
            #pragma unroll
            for (int nj = 0; nj < 8; nj++) {
                float p = __expf(s[nj][r] - mnew);
                s[nj][r] = p;
                rsum += p;
            }
            #pragma unroll
            for (int d = 1; d < 16; d <<= 1) rsum += __shfl_xor(rsum, d);
            l_i[r] = l_i[r] * alpha + rsum;
            #pragma unroll
            for (int nj = 0; nj < 4; nj++) o_acc[nj][r] *= alpha;
            // C-layout -> A-layout transpose via per-wave LDS (2-way banks: free)
            #pragma unroll
            for (int nj = 0; nj < 8; nj++)
                Ps[w][lq * 4 + r][nj * 16 + lr] = (bf16)s[nj][r];
        }

        // O += P @ V (k-dim = 128 keys)
        #pragma unroll
        for (int kk = 0; kk < 4; kk++) {
            bf16x8 pf = *(const bf16x8*)&Ps[w][lr][kk * 32 + lq * 8];
            #pragma unroll
            for (int nj = 0; nj < 4; nj++) {
                bf16x8 vf = *(const bf16x8*)&Vs[vs_off(nj * 16 + lr, kk * 32 + lq * 8)];
                o_acc[nj] = MFMA16(pf, vf, o_acc[nj]);
            }
        }
    }

    #pragma unroll
    for (int r = 0; r < 4; r++) {
        float inv = 1.f / l_i[r];
        int grow = n * 2048 + qt * 128 + w * 16 + lq * 4 + r;
        #pragma unroll
        for (int nj = 0; nj < 4; nj++)
            aout[(size_t)grow * 512 + h * 64 + nj * 16 + lr] = (bf16)(o_acc[nj][r] * inv);
    }
}

extern "C" void kernel_launch(void* const* d_in, const int* in_sizes, int n_in,
                              void* d_out, int out_size, void* d_ws, size_t ws_size,
                              hipStream_t stream) {
    (void)in_sizes; (void)n_in; (void)out_size; (void)ws_size;
    const float* x   = (const float*)d_in[0];
    const float* wq  = (const float*)d_in[1];
    const float* wk  = (const float*)d_in[2];
    const float* wv  = (const float*)d_in[3];
    const float* wo  = (const float*)d_in[4];
    const float* bo  = (const float*)d_in[5];
    const float* g1  = (const float*)d_in[6];
    const float* b1  = (const float*)d_in[7];
    const float* g2  = (const float*)d_in[8];
    const float* b2  = (const float*)d_in[9];
    const float* w1  = (const float*)d_in[10];
    const float* bf1 = (const float*)d_in[11];
    const float* w2  = (const float*)d_in[12];
    const float* bf2 = (const float*)d_in[13];
    float* out = (float*)d_out;

    char* p = (char*)d_ws;
    bf16*  h1     = (bf16*)p;  p += (size_t)8192 * 512 * 2;    // LN1 out (reused for LN2 out)
    bf16*  qkvb   = (bf16*)p;  p += (size_t)8192 * 1536 * 2;   // packed Q|K|V
    bf16*  aout   = (bf16*)p;  p += (size_t)8192 * 512 * 2;    // attention out
    float* x2     = (float*)p; p += (size_t)8192 * 512 * 4;    // post-attn residual (fp32)
    bf16*  ff1    = (bf16*)p;  p += (size_t)8192 * 2048 * 2;   // SiLU(h@w1+b)
    bf16*  wqkv_t = (bf16*)p;  p += (size_t)1536 * 512 * 2;
    bf16*  wo_t   = (bf16*)p;  p += (size_t)512 * 512 * 2;
    bf16*  w1_t   = (bf16*)p;  p += (size_t)2048 * 512 * 2;
    bf16*  w2_t   = (bf16*)p;  p += (size_t)512 * 2048 * 2;

    cvt_qkv_t<<<dim3(24, 8), 256, 0, stream>>>(wq, wk, wv, wqkv_t);
    cvt_t<512, 512><<<dim3(8, 8), 256, 0, stream>>>(wo, wo_t);
    cvt_t<512, 2048><<<dim3(32, 8), 256, 0, stream>>>(w1, w1_t);
    cvt_t<2048, 512><<<dim3(8, 32), 256, 0, stream>>>(w2, w2_t);

    ln_kernel<<<2048, 256, 0, stream>>>(x, g1, b1, h1);
    gemm_k<512, 1536, 0><<<dim3(64, 12), 256, 0, stream>>>(h1, wqkv_t, nullptr, nullptr, qkvb);
    attn_kernel<<<512, 512, 0, stream>>>(qkvb, aout);
    gemm_k<512, 512, 1><<<dim3(64, 4), 256, 0, stream>>>(aout, wo_t, bo, x, x2);
    ln_kernel<<<2048, 256, 0, stream>>>(x2, g2, b2, h1);
    gemm_k<512, 2048, 2><<<dim3(64, 16), 256, 0, stream>>>(h1, w1_t, bf1, nullptr, ff1);
    gemm_k<2048, 512, 1><<<dim3(64, 4), 256, 0, stream>>>(ff1, w2_t, bf2, x2, out);
}